// Round 5
// baseline (1567.924 us; speedup 1.0000x reference)
//
#include <hip/hip_runtime.h>
#include <hip/hip_fp16.h>

#define BATCH   65536
#define NC      16
#define DDIM    64
#define GDIM    32
#define TILE    64

// One block = 16 waves = 16 concepts, one 64-batch tile, lane = batch.
//
// Round-5: combine the three individually counter-verified pieces so the
// live set fits the 64-VGPR budget the allocator insists on (rounds 3/4
// proved it will not grant more; waves_per_eu(4,4) produced an identical
// binary):
//   1) FUSED mask+W1 fold -> hacc[32] (round 1): no m[64]. h_pre is linear
//      in m, m is linear over j-halves, so fold W1 per j-half (+2K FMA).
//   2) Weights fp16 in LDS, read via wave-uniform ds_read_b128 broadcast
//      (round 3): no s_load weight path (round 2's SMEM-drain wall), and
//      the round-3 x swizzle measured ZERO bank conflicts - kept verbatim.
//   3) d-sliced epilogue och[16] (round 2): no o[64]. Peak live set
//      ~55 regs in every phase -> zero scratch expected.
// Round-3/4 counters showed WRITE_SIZE 1.13 GB = 4.3x output from
// m[64]/o[64] spills; this removes them structurally.
extern "C" __global__ void __launch_bounds__(1024)
causal_dag_kernel(const float* __restrict__ x, const float* __restrict__ A,
                  const float* __restrict__ W1, const float* __restrict__ b1,
                  const float* __restrict__ W2, const float* __restrict__ b2,
                  float* __restrict__ out)
{
    __shared__ __align__(16) unsigned char smem_raw[131072];
    __half* xs  = (__half*)smem_raw;             // x tile fp16 (64 KB), then osf
    __half* wsh = (__half*)(smem_raw + 65536);   // W1 then W2, fp16 (64 KB)
    float*  osf = (float*)smem_raw;              // epilogue: 64b x 16c x 16d slice

    const int t    = threadIdx.x;
    const int b0   = blockIdx.x * TILE;
    const int w    = __builtin_amdgcn_readfirstlane(t >> 6);  // concept
    const int lane = t & 63;                                   // batch in tile
    const int sw   = lane & 7;           // low-lane swizzle (d-octet slot)
    const int lhi  = (lane >> 3) & 7;    // high-lane swizzle (j-block)

    const float* b1c = b1 + w * GDIM;
    const float* b2c = b2 + w * DDIM;

    // h_pre accumulator, folded across both j-halves and all d-octets
    float hacc[GDIM];
#pragma unroll
    for (int g = 0; g < GDIM; ++g) hacc[g] = b1c[g];

    const __half* w1w = wsh + w * (GDIM * DDIM);   // [g][d] fp16

    for (int jh = 0; jh < 2; ++jh) {
        // ---- stage 8 concepts of x for the 64-batch tile, fp32->fp16 ----
        // (round-3 addressing verbatim: measured 0 bank conflicts)
#pragma unroll
        for (int p = 0; p < 8; ++p) {
            int f4 = p * 1024 + t;          // float4 index in 128 KB half-tile
            int bb = f4 >> 7;               // batch-local
            int r  = f4 & 127;
            int jp = r >> 4;                // j within half
            int d4 = r & 15;                // 4-float chunk of d
            const float4 v = *(const float4*)(
                x + ((size_t)(b0 + bb) * (NC * DDIM) + (jh * 8 + jp) * DDIM + d4 * 4));
            union { __half2 h2[2]; uint2 u; } pk;
            pk.h2[0] = __floats2half2_rn(v.x, v.y);
            pk.h2[1] = __floats2half2_rn(v.z, v.w);
            int dst = bb * 512 + (jp ^ (bb >> 3)) * 64
                    + (((d4 >> 1) ^ (bb & 7)) << 3) + ((d4 & 1) << 2);
            *(uint2*)(xs + dst) = pk.u;
        }
        if (jh == 0) {
            // ---- stage W1 fp32->fp16 into wsh, layout [c][g][d] ----
#pragma unroll
            for (int p = 0; p < 8; ++p) {
                int f4 = p * 1024 + t;      // 8192 float4 = 32768 floats
                const float4 v = *(const float4*)(W1 + (size_t)f4 * 4);
                union { __half2 h2[2]; uint2 u; } pk;
                pk.h2[0] = __floats2half2_rn(v.x, v.y);
                pk.h2[1] = __floats2half2_rn(v.z, v.w);
                *(uint2*)(wsh + f4 * 4) = pk.u;
            }
        }
        __syncthreads();

        // wave-uniform DAG column for this half (s_loads)
        float a[8];
#pragma unroll
        for (int jp = 0; jp < 8; ++jp) a[jp] = A[(jh * 8 + jp) * NC + w];

        // ---- fused: mc[8] = sum_j a[j]*x[b,j,octet]; hacc += W1.mc ----
        const __half* xb = xs + lane * 512;
#pragma unroll
        for (int dq = 0; dq < 8; ++dq) {
            float mc[8];
#pragma unroll
            for (int k = 0; k < 8; ++k) mc[k] = 0.f;
#pragma unroll
            for (int jp = 0; jp < 8; ++jp) {
                uint4 q = *(const uint4*)(xb + (jp ^ lhi) * 64 + ((dq ^ sw) << 3));
                float2 f0 = __half22float2(*(__half2*)&q.x);
                float2 f1 = __half22float2(*(__half2*)&q.y);
                float2 f2 = __half22float2(*(__half2*)&q.z);
                float2 f3 = __half22float2(*(__half2*)&q.w);
                mc[0] = fmaf(a[jp], f0.x, mc[0]);
                mc[1] = fmaf(a[jp], f0.y, mc[1]);
                mc[2] = fmaf(a[jp], f1.x, mc[2]);
                mc[3] = fmaf(a[jp], f1.y, mc[3]);
                mc[4] = fmaf(a[jp], f2.x, mc[4]);
                mc[5] = fmaf(a[jp], f2.y, mc[5]);
                mc[6] = fmaf(a[jp], f3.x, mc[6]);
                mc[7] = fmaf(a[jp], f3.y, mc[7]);
            }
            // W1 fold for this d-octet: wave-uniform b128 broadcast reads
            const int d0 = dq * 8;
#pragma unroll
            for (int g = 0; g < GDIM; ++g) {
                uint4 qw = *(const uint4*)(w1w + g * DDIM + d0);  // 8 halfs
                const __half* hv = (const __half*)&qw;
                float acc = hacc[g];
                acc = fmaf(__half2float(hv[0]), mc[0], acc);
                acc = fmaf(__half2float(hv[1]), mc[1], acc);
                acc = fmaf(__half2float(hv[2]), mc[2], acc);
                acc = fmaf(__half2float(hv[3]), mc[3], acc);
                acc = fmaf(__half2float(hv[4]), mc[4], acc);
                acc = fmaf(__half2float(hv[5]), mc[5], acc);
                acc = fmaf(__half2float(hv[6]), mc[6], acc);
                acc = fmaf(__half2float(hv[7]), mc[7], acc);
                hacc[g] = acc;
            }
        }
        if (jh == 0) __syncthreads();   // everyone done reading before restage
    }

    // ---- ELU in place ----
#pragma unroll
    for (int g = 0; g < GDIM; ++g)
        hacc[g] = hacc[g] > 0.f ? hacc[g] : (__expf(hacc[g]) - 1.f);

    __syncthreads();   // all waves done reading W1 region and xs

    // ---- stage W2 fp32->fp16 into wsh, layout [c][d][g] ----
#pragma unroll
    for (int p = 0; p < 8; ++p) {
        int f4 = p * 1024 + t;
        const float4 v = *(const float4*)(W2 + (size_t)f4 * 4);
        union { __half2 h2[2]; uint2 u; } pk;
        pk.h2[0] = __floats2half2_rn(v.x, v.y);
        pk.h2[1] = __floats2half2_rn(v.z, v.w);
        *(uint2*)(wsh + f4 * 4) = pk.u;
    }
    __syncthreads();

    const __half* w2w = wsh + w * (DDIM * GDIM);   // [d][g] fp16

    // ---- d-sliced epilogue: 4 rounds of 16 d-values each ----
    for (int r = 0; r < 4; ++r) {
        // compute this lane's 16 outputs for d in [r*16, r*16+16)
        __align__(16) float och[16];
#pragma unroll
        for (int i = 0; i < 16; ++i) {
            const int d = r * 16 + i;
            float acc = b2c[d];
#pragma unroll
            for (int gq = 0; gq < 4; ++gq) {
                uint4 qw = *(const uint4*)(w2w + d * GDIM + gq * 8);  // uniform
                const __half* hv = (const __half*)&qw;
                const int g0 = gq * 8;
#pragma unroll
                for (int k = 0; k < 8; ++k)
                    acc = fmaf(__half2float(hv[k]), hacc[g0 + k], acc);
            }
            och[i] = acc;
        }
        __syncthreads();   // r=0: osf(xs) free; r>0: previous slice stored
        // LDS slice [b][c][dslice]: float4 slot = (c*4+s) ^ b (bijective)
#pragma unroll
        for (int s = 0; s < 4; ++s) {
            const int slot = ((w << 2) + s) ^ lane;
            *(float4*)(osf + lane * 256 + (slot << 2)) = *(const float4*)(och + s * 4);
        }
        __syncthreads();
        // store slice: 16 contiguous floats per (b,c) = full 64B sectors
#pragma unroll
        for (int k = 0; k < 4; ++k) {
            const int f   = k * 1024 + t;   // float4 idx in 64 KB slice
            const int b   = f >> 6;         // batch-local (wave-uniform)
            const int rem = f & 63;         // (c,s) for this lane
            const int c   = rem >> 2;
            const int s   = rem & 3;
            const float4 v = *(const float4*)(osf + b * 256 + ((rem ^ b) << 2));
            *(float4*)(out + (size_t)(b0 + b) * (NC * DDIM) + c * DDIM + r * 16 + s * 4) = v;
        }
    }
}

extern "C" void kernel_launch(void* const* d_in, const int* in_sizes, int n_in,
                              void* d_out, int out_size, void* d_ws, size_t ws_size,
                              hipStream_t stream) {
    const float* x  = (const float*)d_in[0];
    const float* A  = (const float*)d_in[1];
    const float* W1 = (const float*)d_in[2];
    const float* b1 = (const float*)d_in[3];
    const float* W2 = (const float*)d_in[4];
    const float* b2 = (const float*)d_in[5];
    float* out = (float*)d_out;

    causal_dag_kernel<<<BATCH / TILE, 1024, 0, stream>>>(x, A, W1, b1, W2, b2, out);
}